// Round 1
// baseline (308.319 us; speedup 1.0000x reference)
//
#include <hip/hip_runtime.h>

// AlphaCompositionShader: B=4,H=512,W=512,K=8. One thread per pixel.
// Outputs concatenated in d_out (all as float32):
//   [0*P .. 4*P)  composite_image (P x float4)
//   [4*P .. 5*P)  composite_depth
//   [5*P .. 6*P)  composite_label (float-encoded ints)
//   [6*P ..38*P)  human_images (P x 8 x float4)

#define BKG_DEPTH 100.0f
#define KD 8

__global__ __launch_bounds__(256) void alpha_comp_kernel(
    const float4* __restrict__ pc,   // P*8 float4 (rgba per fragment)
    const float4* __restrict__ zb,   // P*2 float4 (8 z values per pixel)
    const int4*  __restrict__ lb,    // P*2 int4  (8 labels per pixel)
    const float* __restrict__ bg,    // 3 floats
    float* __restrict__ out,
    int P)
{
    int pix = blockIdx.x * blockDim.x + threadIdx.x;
    if (pix >= P) return;

    const float bg0 = bg[0], bg1 = bg[1], bg2 = bg[2];

    // ---- loads: per-thread contiguous 128B + 32B + 32B, all 16B vector ops
    float4 c[KD];
#pragma unroll
    for (int k = 0; k < KD; ++k) c[k] = pc[(size_t)pix * KD + k];

    float4 z0 = zb[(size_t)pix * 2 + 0];
    float4 z1 = zb[(size_t)pix * 2 + 1];
    float z[KD] = {z0.x, z0.y, z0.z, z0.w, z1.x, z1.y, z1.z, z1.w};

    int4 l0 = lb[(size_t)pix * 2 + 0];
    int4 l1 = lb[(size_t)pix * 2 + 1];
    int lbl[KD] = {l0.x, l0.y, l0.z, l0.w, l1.x, l1.y, l1.z, l1.w};

    // ---- composite: back-to-front scan (k = K-1 .. 0)
    float r = bg0, g = bg1, b = bg2;
    float a = 0.0f, d = BKG_DEPTH, lab = (float)KD;
#pragma unroll
    for (int k = KD - 1; k >= 0; --k) {
        const float alpha = c[k].w;
        const float ia = 1.0f - alpha;
        r = c[k].x * alpha + r * ia;
        g = c[k].y * alpha + g * ia;
        b = c[k].z * alpha + b * ia;
        a = fmaxf(alpha, a);
        if (z[k] > 0.0f) d = z[k] * alpha + d * ia;
        // labels_f finite iff !(z<0); take label if also alpha>0.5
        if (!(z[k] < 0.0f) && alpha > 0.5f) lab = (float)lbl[k];
    }
    const float labv = (lab > (float)KD - 0.5f) ? -1.0f : lab;

    // ---- human images: per label n, front-most fragment with z>=0 && lbl==n
    float4 hv[KD];
#pragma unroll
    for (int n = 0; n < KD; ++n) {
        float4 gat = make_float4(0.0f, 0.0f, 0.0f, 0.0f);
        // descending k: last assignment wins = smallest matching k (front-most)
#pragma unroll
        for (int k = KD - 1; k >= 0; --k) {
            if (!(z[k] < 0.0f) && lbl[k] == n) gat = c[k];
        }
        const float alpha = gat.w;
        const float ia = 1.0f - alpha;
        hv[n] = make_float4(gat.x * alpha + bg0 * ia,
                            gat.y * alpha + bg1 * ia,
                            gat.z * alpha + bg2 * ia,
                            alpha);
    }

    // ---- stores
    float4* outImg = (float4*)out;                // P float4, coalesced
    outImg[pix] = make_float4(r, g, b, a);
    out[(size_t)4 * P + pix] = d;                 // coalesced scalar
    out[(size_t)5 * P + pix] = labv;              // coalesced scalar
    float4* outH = (float4*)(out + (size_t)6 * P);
#pragma unroll
    for (int n = 0; n < KD; ++n) outH[(size_t)pix * KD + n] = hv[n];
}

extern "C" void kernel_launch(void* const* d_in, const int* in_sizes, int n_in,
                              void* d_out, int out_size, void* d_ws, size_t ws_size,
                              hipStream_t stream) {
    const float4* pc = (const float4*)d_in[0];   // pixel_colors (B,H,W,K,4) f32
    const float4* zb = (const float4*)d_in[1];   // zbuf (B,H,W,K) f32
    const int4*  lb  = (const int4*)d_in[2];     // pixel_labels (B,H,W,K) i32
    const float* bg  = (const float*)d_in[3];    // background_color (3,) f32
    float* out = (float*)d_out;

    const int P = in_sizes[1] / KD;              // B*H*W = 1048576
    const int block = 256;
    const int grid = (P + block - 1) / block;
    alpha_comp_kernel<<<grid, block, 0, stream>>>(pc, zb, lb, bg, out, P);
}

// Round 2
// 292.066 us; speedup vs baseline: 1.0557x; 1.0557x over previous
//
#include <hip/hip_runtime.h>

// AlphaCompositionShader: B=4,H=512,W=512,K=8.
// R1: 8 lanes per pixel (one lane per fragment) so every global access is
// lane-consecutive (16B/lane fully coalesced). Per-pixel scan done in closed
// form with width-8 shuffles:
//   composite rgb = sum_k c_k*a_k*prod_{j<k}(1-a_j) + bg*prod(1-a)
//   depth same with a'_k = (z_k>0 ? a_k : 0), bg=100
//   label = label of min k with (z>=0 && a>0.5), else -1
//   human[n] = front-most fragment with (z>=0 && lbl==n), over bg
// Outputs concatenated in d_out (float32):
//   [0,4P) image | [4P,5P) depth | [5P,6P) label | [6P,38P) human

#define BKG_DEPTH 100.0f
#define KD 8

__global__ __launch_bounds__(256) void alpha_comp_kernel(
    const float4* __restrict__ pc,   // P*8 rgba fragments
    const float*  __restrict__ zb,   // P*8 z
    const int*    __restrict__ lb,   // P*8 labels
    const float*  __restrict__ bg,   // 3 floats
    float* __restrict__ out,
    int P)
{
    const int tid = blockIdx.x * blockDim.x + threadIdx.x;  // global fragment idx
    const int pix = tid >> 3;
    const int kk  = tid & 7;                                // fragment k == human label n
    if (pix >= P) return;

    const float bg0 = bg[0], bg1 = bg[1], bg2 = bg[2];

    // ---- fully coalesced loads (lane-consecutive)
    const float4 c   = pc[tid];
    const float  z   = zb[tid];
    const int    lbl = lb[tid];
    const float  alpha = c.w;

    // ---- composite rgb: weight w_k = a_k * prod_{j<k}(1-a_j)
    float t = 1.0f - alpha;
    float incl = t;                       // inclusive prefix product over group
    {
        float u;
        u = __shfl_up(incl, 1, 8); if (kk >= 1) incl *= u;
        u = __shfl_up(incl, 2, 8); if (kk >= 2) incl *= u;
        u = __shfl_up(incl, 4, 8); if (kk >= 4) incl *= u;
    }
    float pre = __shfl_up(incl, 1, 8); if (kk == 0) pre = 1.0f;
    const float T = __shfl(incl, 7, 8);   // prod over all 8 layers
    const float w = alpha * pre;

    float sr = c.x * w, sg = c.y * w, sb = c.z * w;
    sr += __shfl_xor(sr, 1, 8); sr += __shfl_xor(sr, 2, 8); sr += __shfl_xor(sr, 4, 8);
    sg += __shfl_xor(sg, 1, 8); sg += __shfl_xor(sg, 2, 8); sg += __shfl_xor(sg, 4, 8);
    sb += __shfl_xor(sb, 1, 8); sb += __shfl_xor(sb, 2, 8); sb += __shfl_xor(sb, 4, 8);
    const float outR = sr + bg0 * T;
    const float outG = sg + bg1 * T;
    const float outB = sb + bg2 * T;

    // ---- max alpha
    float am = alpha;
    am = fmaxf(am, __shfl_xor(am, 1, 8));
    am = fmaxf(am, __shfl_xor(am, 2, 8));
    am = fmaxf(am, __shfl_xor(am, 4, 8));

    // ---- depth: layers with z>0 participate, others transparent
    const float a2 = (z > 0.0f) ? alpha : 0.0f;
    float incl2 = 1.0f - a2;
    {
        float u;
        u = __shfl_up(incl2, 1, 8); if (kk >= 1) incl2 *= u;
        u = __shfl_up(incl2, 2, 8); if (kk >= 2) incl2 *= u;
        u = __shfl_up(incl2, 4, 8); if (kk >= 4) incl2 *= u;
    }
    float pre2 = __shfl_up(incl2, 1, 8); if (kk == 0) pre2 = 1.0f;
    const float T2 = __shfl(incl2, 7, 8);
    float sd = z * (a2 * pre2);           // 0 when a2==0
    sd += __shfl_xor(sd, 1, 8); sd += __shfl_xor(sd, 2, 8); sd += __shfl_xor(sd, 4, 8);
    const float outD = sd + BKG_DEPTH * T2;

    // ---- composite label: min k with (z>=0 && alpha>0.5)
    const bool validL = !(z < 0.0f);
    const unsigned long long bal = __ballot(validL && (alpha > 0.5f));
    const int lane = threadIdx.x & 63;
    const unsigned int grpByte = (unsigned int)((bal >> (lane & ~7)) & 0xFFull);
    const int jlab = grpByte ? (__ffs(grpByte) - 1) : 0;
    const int lsel = __shfl(lbl, jlab, 8);
    const float labv = grpByte ? (float)lsel : -1.0f;

    // ---- human image for label n = kk: front-most fragment with enc==kk
    const int enc = validL ? lbl : 255;
    int jm = -1, ej;
    ej = __shfl(enc, 7, 8); if (ej == kk) jm = 7;
    ej = __shfl(enc, 6, 8); if (ej == kk) jm = 6;
    ej = __shfl(enc, 5, 8); if (ej == kk) jm = 5;
    ej = __shfl(enc, 4, 8); if (ej == kk) jm = 4;
    ej = __shfl(enc, 3, 8); if (ej == kk) jm = 3;
    ej = __shfl(enc, 2, 8); if (ej == kk) jm = 2;
    ej = __shfl(enc, 1, 8); if (ej == kk) jm = 1;
    ej = __shfl(enc, 0, 8); if (ej == kk) jm = 0;
    const int src = (jm >= 0) ? jm : 0;
    float gx = __shfl(c.x, src, 8);
    float gy = __shfl(c.y, src, 8);
    float gz = __shfl(c.z, src, 8);
    float gw = __shfl(c.w, src, 8);
    if (jm < 0) { gx = 0.0f; gy = 0.0f; gz = 0.0f; gw = 0.0f; }
    const float ia = 1.0f - gw;
    const float4 hv = make_float4(gx * gw + bg0 * ia,
                                  gy * gw + bg1 * ia,
                                  gz * gw + bg2 * ia,
                                  gw);

    // ---- stores
    ((float4*)(out + (size_t)6 * P))[tid] = hv;        // fully coalesced, 128 MiB
    if (kk == 0) ((float4*)out)[pix] = make_float4(outR, outG, outB, am);  // contiguous 16B per group
    if (kk == 1) out[(size_t)4 * P + pix] = outD;      // contiguous 4B per group
    if (kk == 2) out[(size_t)5 * P + pix] = labv;      // contiguous 4B per group
}

extern "C" void kernel_launch(void* const* d_in, const int* in_sizes, int n_in,
                              void* d_out, int out_size, void* d_ws, size_t ws_size,
                              hipStream_t stream) {
    const float4* pc = (const float4*)d_in[0];   // pixel_colors (B,H,W,K,4) f32
    const float*  zb = (const float*)d_in[1];    // zbuf (B,H,W,K) f32
    const int*    lb = (const int*)d_in[2];      // pixel_labels (B,H,W,K) i32
    const float*  bg = (const float*)d_in[3];    // background_color (3,) f32
    float* out = (float*)d_out;

    const int P = in_sizes[1] / KD;              // B*H*W = 1048576
    const int total = P * KD;                    // one thread per fragment
    const int block = 256;
    const int grid = (total + block - 1) / block;
    alpha_comp_kernel<<<grid, block, 0, stream>>>(pc, zb, lb, bg, out, P);
}